// Round 7
// baseline (1719.072 us; speedup 1.0000x reference)
//
#include <hip/hip_runtime.h>
#include <math.h>

#define T_TOK 2048
#define NE 64
#define KTOP 8
#define CAPC 512
#define DIN 768
#define HD 2048
#define BTD 256
#define OD 768

typedef short bf16x8 __attribute__((ext_vector_type(8)));
typedef float f32x4 __attribute__((ext_vector_type(4)));

__device__ __forceinline__ unsigned short f2bf(float f) {
  unsigned u = __float_as_uint(f);
  u += 0x7FFF + ((u >> 16) & 1);   // round-to-nearest-even
  return (unsigned short)(u >> 16);
}
__device__ __forceinline__ unsigned cvt2(float a, float b) {
  unsigned r;
  asm("v_cvt_pk_bf16_f32 %0, %1, %2" : "=v"(r) : "v"(a), "v"(b));
  return r;   // lo = bf16(a), hi = bf16(b)
}
__device__ __forceinline__ float gelu_exact(float v) {
  return 0.5f * v * (1.0f + erff(v * 0.7071067811865476f));
}
__device__ __forceinline__ void glds16(unsigned short* lds, const unsigned short* g) {
  __builtin_amdgcn_global_load_lds(
      (const __attribute__((address_space(1))) void*)g,
      (__attribute__((address_space(3))) void*)lds, 16, 0, 0);
}

// ---------------- x fp32 -> bf16 ---------------------------------------------------
__global__ __launch_bounds__(256) void cvt_x(const float* __restrict__ x,
                                             unsigned short* __restrict__ xb) {
  int i = blockIdx.x * 256 + threadIdx.x;
  float4 v = ((const float4*)x)[i];
  ushort4 o;
  o.x = f2bf(v.x); o.y = f2bf(v.y); o.z = f2bf(v.z); o.w = f2bf(v.w);
  ((ushort4*)xb)[i] = o;
}

// ---------------- DENSE weight retile: fp32 [K][N] -> bf16 GEMM-native 8KB tiles ----
// Block (t, e) covers k-rows [32t, 32t+32). Four phases; each phase reads 8 FULL
// rows contiguously (dense HBM stream), then writes, for every column n, the 16B
// chunk holding rows 8q..8q+7 at tile position n'*32 + s*8  (s = (q + ((n'>>1)&3))&3,
// the chunk-permute swizzle moe_gemm_t's conflict-free fragment reads expect).
template<int KD, int ND>
__global__ __launch_bounds__(256) void retile_dense(const float* __restrict__ W,
                                                    unsigned short* __restrict__ Bt) {
  constexpr int KT = KD / 32;
  constexpr int NP = ND / 128;
  const int t = blockIdx.x;
  const int e = blockIdx.y;
  const int tid = threadIdx.x;
  __shared__ float L[8 * ND];
  const float* w0 = W + ((size_t)e * KD + 32 * t) * ND;
  unsigned short* out0 = Bt + (((size_t)e * NP) * KT + t) * 4096;
  for (int q = 0; q < 4; q++) {
    const float4* src = (const float4*)(w0 + (size_t)(8 * q) * ND);
    #pragma unroll 4
    for (int i = tid; i < 8 * ND / 4; i += 256) ((float4*)L)[i] = src[i];
    __syncthreads();
    for (int i = tid; i < ND; i += 256) {
      int p = i >> 7, n = i & 127;
      int s = (q + ((n >> 1) & 3)) & 3;
      union { bf16x8 v; unsigned u[4]; } pk;
      #pragma unroll
      for (int h = 0; h < 4; h++)
        pk.u[h] = cvt2(L[(2 * h) * ND + i], L[(2 * h + 1) * ND + i]);
      *(bf16x8*)&out0[(size_t)p * KT * 4096 + n * 32 + s * 8] = pk.v;
    }
    __syncthreads();
  }
}

// ---------------- router: fp32 logits, noisy top-8, softmax, gate/slot matrices ----
__global__ __launch_bounds__(256) void router_kernel(
    const float* __restrict__ x, const float* __restrict__ noise,
    const float* __restrict__ Wr, const float* __restrict__ br,
    const float* __restrict__ Wn, const float* __restrict__ bn,
    float* __restrict__ gate, int* __restrict__ slotm)
{
  __shared__ float xs[8][DIN];
  __shared__ float wrs[64][NE];
  __shared__ float wns[64][NE];
  const int tid = threadIdx.x;
  const int t0 = blockIdx.x * 8;
  for (int i = tid; i < 8 * (DIN / 4); i += 256) {
    int tt = i / (DIN / 4), c = i % (DIN / 4);
    ((float4*)xs[tt])[c] = ((const float4*)(x + (size_t)(t0 + tt) * DIN))[c];
  }
  const int lane = tid & 63;
  const int wv = tid >> 6;
  const int e = lane;
  const int ta = 2 * wv, tb = ta + 1;
  float ar0 = br[e], ar1 = ar0, an0 = bn[e], an1 = an0;
  for (int d0 = 0; d0 < DIN; d0 += 64) {
    __syncthreads();
    for (int i = tid; i < 64 * NE / 4; i += 256) {
      int dd = i >> 4, c4 = (i & 15) * 4;
      *(float4*)&wrs[dd][c4] = *(const float4*)&Wr[(size_t)(d0 + dd) * NE + c4];
      *(float4*)&wns[dd][c4] = *(const float4*)&Wn[(size_t)(d0 + dd) * NE + c4];
    }
    __syncthreads();
    #pragma unroll 8
    for (int dd = 0; dd < 64; dd++) {
      float wr = wrs[dd][e], wn = wns[dd][e];
      float xa = xs[ta][d0 + dd], xb = xs[tb][d0 + dd];
      ar0 = fmaf(xa, wr, ar0); ar1 = fmaf(xb, wr, ar1);
      an0 = fmaf(xa, wn, an0); an1 = fmaf(xb, wn, an1);
    }
  }
  #pragma unroll
  for (int s = 0; s < 2; s++) {
    int t = t0 + ta + s;
    float lr = s ? ar1 : ar0;
    float lnv = s ? an1 : an0;
    float sp = fmaxf(lnv, 0.f) + log1pf(expf(-fabsf(lnv)));   // softplus, overflow-safe
    float v = lr + noise[(size_t)t * NE + e] * sp;
    float cur = v;
    float topv[KTOP]; int topi[KTOP];
    #pragma unroll
    for (int j = 0; j < KTOP; j++) {
      float bv = cur; int bi = e;
      #pragma unroll
      for (int off = 32; off > 0; off >>= 1) {
        float ov = __shfl_xor(bv, off);
        int   oi = __shfl_xor(bi, off);
        if (ov > bv || (ov == bv && oi < bi)) { bv = ov; bi = oi; }
      }
      topv[j] = bv; topi[j] = bi;
      if (e == bi) cur = -INFINITY;
    }
    float mx = topv[0], se = 0.f, pv[KTOP];
    #pragma unroll
    for (int j = 0; j < KTOP; j++) { pv[j] = expf(topv[j] - mx); se += pv[j]; }
    float inv = 1.f / se;
    float g = 0.f; int sl = -1;
    #pragma unroll
    for (int j = 0; j < KTOP; j++) if (topi[j] == e) { g = pv[j] * inv; sl = j; }
    gate[(size_t)t * NE + e] = (sl >= 0) ? g : 0.f;
    slotm[(size_t)t * NE + e] = sl;
  }
}

// ---------------- dispatch: stable per-expert compaction (== stable argsort) -------
__global__ __launch_bounds__(256) void dispatch_kernel(
    const float* __restrict__ gate, const int* __restrict__ slotm,
    int* __restrict__ tok_idx, float* __restrict__ tok_g,
    int* __restrict__ tok_slot, int* __restrict__ counts)
{
  const int e = blockIdx.x;
  const int tid = threadIdx.x;
  __shared__ int wave_off[4];
  int base = 0;
  for (int t0 = 0; t0 < T_TOK; t0 += 256) {
    int t = t0 + tid;
    float g = gate[(size_t)t * NE + e];
    bool p = g > 0.f;
    unsigned long long m = __ballot(p);
    int wv = tid >> 6, lane = tid & 63;
    int pre = __popcll(m & ((1ull << lane) - 1ull));
    if (lane == 0) wave_off[wv] = __popcll(m);
    __syncthreads();
    int off = 0;
    for (int w = 0; w < wv; w++) off += wave_off[w];
    int tot = wave_off[0] + wave_off[1] + wave_off[2] + wave_off[3];
    if (p) {
      int pos = base + off + pre;
      if (pos < CAPC) {
        tok_idx[(size_t)e * CAPC + pos] = t;
        tok_g[(size_t)e * CAPC + pos] = g;
        tok_slot[(size_t)e * CAPC + pos] = slotm[(size_t)t * NE + e];
      }
    }
    base += tot;
    __syncthreads();
  }
  if (tid == 0) counts[e] = min(base, CAPC);
}

// ============== GEMM with retiled bf16 B: 256x128x32, both operands gload_lds ======
// 512 thr / 8 waves; 3 LDS buffers; 3 gload_lds per thread per iter; vmcnt(3) depth-2
// pipeline, one barrier per iter. B tiles are contiguous 8KB (dense HBM stream).
template<int KD, int ND, bool AGATHER, int EPI>
__global__ __launch_bounds__(512, 2) void moe_gemm_t(
    const unsigned short* __restrict__ Abf, const unsigned short* __restrict__ Bt,
    const float* __restrict__ bias, void* __restrict__ Outp,
    const int* __restrict__ tok_idx, const float* __restrict__ tok_g,
    const int* __restrict__ tok_slot, const int* __restrict__ counts)
{
  constexpr int NK = KD / 32;
  constexpr int NP = ND / 128;
  const int e = blockIdx.z;
  const int cnt = counts[e];
  const int m0 = blockIdx.y * 256;
  if (m0 >= cnt) return;
  const int p = blockIdx.x;
  const int n0 = p * 128;
  const int tid = threadIdx.x;
  const int lane = tid & 63, wave = tid >> 6;

  __shared__ unsigned short AL[3][256][32];   // 48 KB
  __shared__ unsigned short BL[3][128][32];   // 24 KB
  __shared__ int   s_tok[EPI == 2 ? 256 : 1];
  __shared__ float s_g[EPI == 2 ? 256 : 1];
  __shared__ int   s_slot[EPI == 2 ? 256 : 1];

  if (EPI == 2 && tid < 256) {
    int gr = m0 + tid;
    if (gr < cnt) {
      s_tok[tid]  = tok_idx[(size_t)e * CAPC + gr];
      s_g[tid]    = tok_g[(size_t)e * CAPC + gr];
      s_slot[tid] = tok_slot[(size_t)e * CAPC + gr];
    }
  }

  // A staging: wave stages rows [32w,32w+32) in 2 calls; lane -> row 32w+16j+(lane>>2),
  // slot lane&3 holds global chunk ((lane&3)-((row>>1)&3))&3  (conflict-free reads)
  size_t a_src[2];
  #pragma unroll
  for (int j = 0; j < 2; j++) {
    int r = 32 * wave + 16 * j + (lane >> 2);
    int c = ((lane & 3) - ((r >> 1) & 3)) & 3;
    size_t rowb;
    if (AGATHER) {
      int gr = m0 + r;
      int tk = (gr < cnt) ? tok_idx[(size_t)e * CAPC + gr] : 0;
      rowb = (size_t)tk * KD;
    } else {
      rowb = ((size_t)e * CAPC + m0 + r) * KD;
    }
    a_src[j] = rowb + 8 * c;
  }
  const int a_dst0 = (32 * wave) * 32;
  const int a_dst1 = (32 * wave + 16) * 32;
  // B staging: wave stages 1KB of the contiguous 8KB tile
  const unsigned short* b_src = Bt + ((size_t)(e * NP + p) * NK) * 4096 + wave * 512 + lane * 8;
  const int b_dst = wave * 512;

  auto stage = [&](int t, unsigned short* Abuf, unsigned short* Bbuf) {
    glds16(Abuf + a_dst0, Abf + a_src[0] + (size_t)t * 32);
    glds16(Abuf + a_dst1, Abf + a_src[1] + (size_t)t * 32);
    glds16(Bbuf + b_dst, b_src + (size_t)t * 4096);
  };

  const int wm = 64 * (wave >> 1), wn = 64 * (wave & 1);
  const int li = lane & 15, lg = lane >> 4;
  const int kx = 8 * ((lg + ((li >> 1) & 3)) & 3);

  f32x4 acc[4][4];
  #pragma unroll
  for (int i = 0; i < 4; i++)
    #pragma unroll
    for (int j = 0; j < 4; j++) acc[i][j] = (f32x4){0.f, 0.f, 0.f, 0.f};

  auto step = [&](const unsigned short* Abuf, const unsigned short* Bbuf) {
    bf16x8 afr[4], bfr[4];
    #pragma unroll
    for (int mi = 0; mi < 4; mi++)
      afr[mi] = *(const bf16x8*)&Abuf[(wm + 16 * mi + li) * 32 + kx];
    #pragma unroll
    for (int ni = 0; ni < 4; ni++)
      bfr[ni] = *(const bf16x8*)&Bbuf[(wn + 16 * ni + li) * 32 + kx];
    __builtin_amdgcn_s_setprio(1);
    #pragma unroll
    for (int mi = 0; mi < 4; mi++)
      #pragma unroll
      for (int ni = 0; ni < 4; ni++)
        acc[mi][ni] = __builtin_amdgcn_mfma_f32_16x16x32_bf16(afr[mi], bfr[ni], acc[mi][ni], 0, 0, 0);
    __builtin_amdgcn_s_setprio(0);
  };

  unsigned short *A0 = &AL[0][0][0], *A1 = &AL[1][0][0], *A2 = &AL[2][0][0];
  unsigned short *B0 = &BL[0][0][0], *B1 = &BL[1][0][0], *B2 = &BL[2][0][0];

  stage(0, A0, B0);
  stage(1, A1, B1);
  asm volatile("s_waitcnt vmcnt(3)" ::: "memory");   // tile 0 landed
  __builtin_amdgcn_s_barrier();

  for (int kt = 0; kt < NK; kt++) {
    const int tn = (kt + 2 < NK) ? kt + 2 : NK - 1;
    stage(tn, A2, B2);              // buf (kt+2)%3: disjoint from tile kt's buf
    step(A0, B0);                   // tile kt
    asm volatile("s_waitcnt vmcnt(3)" ::: "memory");  // tile kt+1 landed
    __builtin_amdgcn_s_barrier();
    unsigned short* ta = A0; A0 = A1; A1 = A2; A2 = ta;
    unsigned short* tb = B0; B0 = B1; B1 = B2; B2 = tb;
  }
  asm volatile("s_waitcnt vmcnt(0)" ::: "memory");   // drain before WG exit

  const float* bpb = bias + (size_t)e * ND;
  #pragma unroll
  for (int mi = 0; mi < 4; mi++) {
    #pragma unroll
    for (int ni = 0; ni < 4; ni++) {
      const int ncol = n0 + wn + ni * 16 + li;
      const float bb = bpb[ncol];
      #pragma unroll
      for (int q = 0; q < 4; q++) {
        const int r = wm + mi * 16 + lg * 4 + q;
        const int gr = m0 + r;
        if (gr < cnt) {
          float v = acc[mi][ni][q] + bb;
          if (EPI == 0) {
            v = gelu_exact(v);
            ((unsigned short*)Outp)[((size_t)e * CAPC + gr) * ND + ncol] = f2bf(v);
          } else if (EPI == 1) {
            ((unsigned short*)Outp)[((size_t)e * CAPC + gr) * ND + ncol] = f2bf(v);
          } else {
            ((float*)Outp)[((size_t)s_tok[r] * KTOP + s_slot[r]) * OD + ncol] = v * s_g[r];
          }
        }
      }
    }
  }
}

// ============== BIG expert GEMM (r5): 256x128x32 fp32-B, fallback only =============
template<int KD, int NDT, bool AGATHER, int EPI>
__global__ __launch_bounds__(512, 1) void moe_gemm_big(
    const unsigned short* __restrict__ Abf, const float* __restrict__ Bw,
    const float* __restrict__ bias, void* __restrict__ Outp,
    const int* __restrict__ tok_idx, const float* __restrict__ tok_g,
    const int* __restrict__ tok_slot, const int* __restrict__ counts)
{
  constexpr int NK = KD / 32;
  static_assert(NK % 4 == 0 && NK >= 8, "NK must be multiple of 4");
  const int e = blockIdx.z;
  const int cnt = counts[e];
  const int m0 = blockIdx.y * 256;
  if (m0 >= cnt) return;
  const int n0 = blockIdx.x * 128;
  const int tid = threadIdx.x;
  const int lane = tid & 63, wave = tid >> 6;

  __shared__ unsigned short AL[4][256][32];
  __shared__ unsigned short BL[4][128][40];
  __shared__ int   s_tok[256];
  __shared__ float s_g[256];
  __shared__ int   s_slot[256];

  if (EPI == 2 && tid < 256) {
    int gr = m0 + tid;
    if (gr < cnt) {
      s_tok[tid]  = tok_idx[(size_t)e * CAPC + gr];
      s_g[tid]    = tok_g[(size_t)e * CAPC + gr];
      s_slot[tid] = tok_slot[(size_t)e * CAPC + gr];
    }
  }

  const bool isB = wave < 4;
  const int  w4  = wave & 3;

  const float* bp = Bw + (size_t)e * KD * NDT + (size_t)(8 * w4) * NDT + n0 + 2 * lane;
  float2 breg[4][8];

  size_t a_off[4];
  if (!isB) {
    #pragma unroll
    for (int q = 0; q < 4; q++) {
      int r  = w4 * 64 + q * 16 + (lane >> 2);
      int cq = ((lane & 3) - (r >> 1)) & 3;
      size_t rowb;
      if (AGATHER) {
        int gr = m0 + r;
        int tk = (gr < cnt) ? tok_idx[(size_t)e * CAPC + gr] : 0;
        rowb = (size_t)tk * KD;
      } else {
        rowb = ((size_t)e * CAPC + m0 + r) * KD;
      }
      a_off[q] = rowb + 8 * cq;
    }
  }

  auto stageA = [&](int t, int s) {
    #pragma unroll
    for (int q = 0; q < 4; q++)
      glds16(&AL[s][0][0] + w4 * 2048 + q * 512, Abf + a_off[q] + (size_t)t * 32);
  };
  auto loadB = [&](int t, int p) {
    const float* pb = bp + (size_t)t * 32 * NDT;
    #pragma unroll
    for (int j = 0; j < 8; j++) breg[p][j] = *(const float2*)(pb + (size_t)j * NDT);
  };
  auto writeB = [&](int s, int p) {
    uint4 rx, ry;
    rx.x = cvt2(breg[p][0].x, breg[p][1].x); rx.y = cvt2(breg[p][2].x, breg[p][3].x);
    rx.z = cvt2(breg[p][4].x, breg[p][5].x); rx.w = cvt2(breg[p][6].x, breg[p][7].x);
    ry.x = cvt2(breg[p][0].y, breg[p][1].y); ry.y = cvt2(breg[p][2].y, breg[p][3].y);
    ry.z = cvt2(breg[p][4].y, breg[p][5].y); ry.w = cvt2(breg[p][6].y, breg[p][7].y);
    *(uint4*)&BL[s][2 * lane][8 * w4]     = rx;
    *(uint4*)&BL[s][2 * lane + 1][8 * w4] = ry;
  };

  const int wm = (wave >> 1) * 64;
  const int wn = (wave & 1) * 64;
  const int li = lane & 15, lg = lane >> 4;
  const int kxa = 8 * ((lg + ((li >> 1) & 3)) & 3);

  f32x4 acc[4][4];
  #pragma unroll
  for (int i = 0; i < 4; i++)
    #pragma unroll
    for (int j = 0; j < 4; j++) acc[i][j] = (f32x4){0.f, 0.f, 0.f, 0.f};

  auto step = [&](int s) {
    bf16x8 afr[4], bfr[4];
    #pragma unroll
    for (int mi = 0; mi < 4; mi++)
      afr[mi] = *(const bf16x8*)&AL[s][wm + mi * 16 + li][kxa];
    #pragma unroll
    for (int ni = 0; ni < 4; ni++)
      bfr[ni] = *(const bf16x8*)&BL[s][wn + ni * 16 + li][lg * 8];
    __builtin_amdgcn_s_setprio(1);
    #pragma unroll
    for (int mi = 0; mi < 4; mi++)
      #pragma unroll
      for (int ni = 0; ni < 4; ni++)
        acc[mi][ni] = __builtin_amdgcn_mfma_f32_16x16x32_bf16(afr[mi], bfr[ni], acc[mi][ni], 0, 0, 0);
    __builtin_amdgcn_s_setprio(0);
  };

  if (isB) {
    loadB(0, 0); loadB(1, 1); loadB(2, 2);
    asm volatile("s_waitcnt vmcnt(16)" ::: "memory");
    writeB(0, 0);
    asm volatile("s_waitcnt lgkmcnt(0)" ::: "memory");
  } else {
    stageA(0, 0); stageA(1, 1); stageA(2, 2);
    asm volatile("s_waitcnt vmcnt(8)" ::: "memory");
  }
  __builtin_amdgcn_s_barrier();

  #define SUBITER(p)                                                        \
    do {                                                                    \
      const int jj = jb + (p);                                              \
      if (isB) loadB(min(jj + 3, NK - 1), ((p) + 3) & 3);                   \
      else     stageA(min(jj + 3, NK - 1), ((p) + 3) & 3);                  \
      step(p);                                                              \
      if (isB) {                                                            \
        asm volatile("s_waitcnt vmcnt(16)" ::: "memory");                   \
        writeB(((p) + 1) & 3, ((p) + 1) & 3);                               \
        asm volatile("s_waitcnt lgkmcnt(0)" ::: "memory");                  \
      } else {                                                              \
        asm volatile("s_waitcnt vmcnt(8)" ::: "memory");                    \
      }                                                                     \
      __builtin_amdgcn_s_barrier();                                        \
    } while (0)

  for (int jb = 0; jb < NK; jb += 4) {
    SUBITER(0); SUBITER(1); SUBITER(2); SUBITER(3);
  }
  #undef SUBITER
  asm volatile("s_waitcnt vmcnt(0)" ::: "memory");

  const float* bpb = bias + (size_t)e * NDT;
  #pragma unroll
  for (int mi = 0; mi < 4; mi++) {
    #pragma unroll
    for (int ni = 0; ni < 4; ni++) {
      const int ncol = n0 + wn + ni * 16 + li;
      const float bb = bpb[ncol];
      #pragma unroll
      for (int q = 0; q < 4; q++) {
        const int r = wm + mi * 16 + lg * 4 + q;
        const int gr = m0 + r;
        if (gr < cnt) {
          float v = acc[mi][ni][q] + bb;
          if (EPI == 0) {
            v = gelu_exact(v);
            ((unsigned short*)Outp)[((size_t)e * CAPC + gr) * NDT + ncol] = f2bf(v);
          } else if (EPI == 1) {
            ((unsigned short*)Outp)[((size_t)e * CAPC + gr) * NDT + ncol] = f2bf(v);
          } else {
            ((float*)Outp)[((size_t)s_tok[r] * KTOP + s_slot[r]) * OD + ncol] = v * s_g[r];
          }
        }
      }
    }
  }
}

// ---------------- combine 8 slots + LayerNorm -------------------------------------
__global__ __launch_bounds__(256) void combine_ln(
    const float* __restrict__ yd, const float* __restrict__ lw,
    const float* __restrict__ lb, float* __restrict__ out)
{
  const int t = blockIdx.x, tid = threadIdx.x;
  float v[3];
  #pragma unroll
  for (int i = 0; i < 3; i++) {
    const int c = tid + 256 * i;
    float s = 0.f;
    #pragma unroll
    for (int j = 0; j < KTOP; j++) s += yd[((size_t)t * KTOP + j) * OD + c];
    v[i] = s;
  }
  float s1 = v[0] + v[1] + v[2];
  float s2 = v[0] * v[0] + v[1] * v[1] + v[2] * v[2];
  #pragma unroll
  for (int off = 32; off > 0; off >>= 1) {
    s1 += __shfl_xor(s1, off);
    s2 += __shfl_xor(s2, off);
  }
  __shared__ float as1[4], as2[4];
  const int lane = tid & 63, wv = tid >> 6;
  if (lane == 0) { as1[wv] = s1; as2[wv] = s2; }
  __syncthreads();
  s1 = as1[0] + as1[1] + as1[2] + as1[3];
  s2 = as2[0] + as2[1] + as2[2] + as2[3];
  const float mu = s1 * (1.f / OD);
  const float var = s2 * (1.f / OD) - mu * mu;
  const float rstd = rsqrtf(var + 1e-5f);
  #pragma unroll
  for (int i = 0; i < 3; i++) {
    const int c = tid + 256 * i;
    out[(size_t)t * OD + c] = (v[i] - mu) * rstd * lw[c] + lb[c];
  }
}

extern "C" void kernel_launch(void* const* d_in, const int* in_sizes, int n_in,
                              void* d_out, int out_size, void* d_ws, size_t ws_size,
                              hipStream_t stream) {
  const float* x     = (const float*)d_in[0];
  const float* noise = (const float*)d_in[1];
  const float* Wr    = (const float*)d_in[2];
  const float* br    = (const float*)d_in[3];
  const float* Wn    = (const float*)d_in[4];
  const float* bn    = (const float*)d_in[5];
  const float* W1    = (const float*)d_in[6];
  const float* b1    = (const float*)d_in[7];
  const float* W2    = (const float*)d_in[8];
  const float* b2    = (const float*)d_in[9];
  const float* W3    = (const float*)d_in[10];
  const float* b3    = (const float*)d_in[11];
  const float* Wo    = (const float*)d_in[12];
  const float* bo    = (const float*)d_in[13];
  const float* lw    = (const float*)d_in[14];
  const float* lb    = (const float*)d_in[15];
  float* out = (float*)d_out;

  char* ws = (char*)d_ws;
  constexpr size_t OFF_GATE = 0;
  constexpr size_t OFF_SLOT = OFF_GATE + (size_t)T_TOK * NE * 4;
  constexpr size_t OFF_TIDX = OFF_SLOT + (size_t)T_TOK * NE * 4;
  constexpr size_t OFF_TG   = OFF_TIDX + (size_t)NE * CAPC * 4;
  constexpr size_t OFF_TSL  = OFF_TG + (size_t)NE * CAPC * 4;
  constexpr size_t OFF_CNT  = OFF_TSL + (size_t)NE * CAPC * 4;
  constexpr size_t OFF_YD   = ((OFF_CNT + NE * 4) + 255) & ~(size_t)255;
  constexpr size_t SZ_YD    = (size_t)T_TOK * KTOP * OD * 4;
  constexpr size_t OFF_H1   = OFF_YD + SZ_YD;
  constexpr size_t OFF_H2   = OFF_H1 + (size_t)NE * CAPC * HD * 2;
  constexpr size_t OFF_H3   = OFF_H2 + (size_t)NE * CAPC * HD * 2;
  constexpr size_t OFF_XBF  = OFF_H3 + (size_t)NE * CAPC * BTD * 2;
  constexpr size_t OFF_W2T  = ((OFF_XBF + (size_t)T_TOK * DIN * 2) + 255) & ~(size_t)255;
  constexpr size_t SZ_W2T   = (size_t)NE * (HD / 128) * (HD / 32) * 4096 * 2;   // 537 MB
  constexpr size_t OFF_W3T  = OFF_W2T + SZ_W2T;
  constexpr size_t SZ_W3T   = (size_t)NE * (BTD / 128) * (HD / 32) * 4096 * 2;  // 67 MB
  constexpr size_t OFF_WOT  = OFF_W3T + SZ_W3T;
  constexpr size_t SZ_WOT   = (size_t)NE * (OD / 128) * (BTD / 32) * 4096 * 2;  // 25 MB
  constexpr size_t OFF_W1T  = OFF_WOT + SZ_WOT;
  constexpr size_t SZ_W1T   = (size_t)NE * (HD / 128) * (DIN / 32) * 4096 * 2;  // 201 MB
  constexpr size_t NEED     = OFF_W1T + SZ_W1T;

  float* gate = (float*)(ws + OFF_GATE);
  int*   slot = (int*)(ws + OFF_SLOT);
  int*   tidx = (int*)(ws + OFF_TIDX);
  float* tg   = (float*)(ws + OFF_TG);
  int*   tsl  = (int*)(ws + OFF_TSL);
  int*   cnts = (int*)(ws + OFF_CNT);
  float* yd   = (float*)(ws + OFF_YD);
  unsigned short* h1  = (unsigned short*)(ws + OFF_H1);
  unsigned short* h2  = (unsigned short*)(ws + OFF_H2);
  unsigned short* h3  = (unsigned short*)(ws + OFF_H3);
  unsigned short* xbf = (unsigned short*)(ws + OFF_XBF);
  unsigned short* w2t = (unsigned short*)(ws + OFF_W2T);
  unsigned short* w3t = (unsigned short*)(ws + OFF_W3T);
  unsigned short* wot = (unsigned short*)(ws + OFF_WOT);
  unsigned short* w1t = (unsigned short*)(ws + OFF_W1T);

  hipMemsetAsync(yd, 0, SZ_YD, stream);
  cvt_x<<<T_TOK * DIN / 4 / 256, 256, 0, stream>>>(x, xbf);

  if (ws_size >= NEED) {
    // dense-retile path: every weight byte crosses HBM in contiguous order
    retile_dense<DIN, HD><<<dim3(DIN / 32, NE), 256, 0, stream>>>(W1, w1t);
    retile_dense<HD, HD><<<dim3(HD / 32, NE), 256, 0, stream>>>(W2, w2t);
    retile_dense<HD, BTD><<<dim3(HD / 32, NE), 256, 0, stream>>>(W3, w3t);
    retile_dense<BTD, OD><<<dim3(BTD / 32, NE), 256, 0, stream>>>(Wo, wot);
    router_kernel<<<T_TOK / 8, 256, 0, stream>>>(x, noise, Wr, br, Wn, bn, gate, slot);
    dispatch_kernel<<<NE, 256, 0, stream>>>(gate, slot, tidx, tg, tsl, cnts);
    moe_gemm_t<DIN, HD, true, 0><<<dim3(HD / 128, CAPC / 256, NE), 512, 0, stream>>>(
        xbf, w1t, b1, h1, tidx, tg, tsl, cnts);
    moe_gemm_t<HD, HD, false, 0><<<dim3(HD / 128, CAPC / 256, NE), 512, 0, stream>>>(
        h1, w2t, b2, h2, tidx, tg, tsl, cnts);
    moe_gemm_t<HD, BTD, false, 1><<<dim3(BTD / 128, CAPC / 256, NE), 512, 0, stream>>>(
        h2, w3t, b3, h3, tidx, tg, tsl, cnts);
    moe_gemm_t<BTD, OD, false, 2><<<dim3(OD / 128, CAPC / 256, NE), 512, 0, stream>>>(
        h3, wot, bo, yd, tidx, tg, tsl, cnts);
  } else {
    // fallback: r5 path (no extra workspace needed)
    router_kernel<<<T_TOK / 8, 256, 0, stream>>>(x, noise, Wr, br, Wn, bn, gate, slot);
    dispatch_kernel<<<NE, 256, 0, stream>>>(gate, slot, tidx, tg, tsl, cnts);
    moe_gemm_big<DIN, HD, true, 0><<<dim3(HD / 128, CAPC / 256, NE), 512, 0, stream>>>(
        xbf, W1, b1, h1, tidx, tg, tsl, cnts);
    moe_gemm_big<HD, HD, false, 0><<<dim3(HD / 128, CAPC / 256, NE), 512, 0, stream>>>(
        h1, W2, b2, h2, tidx, tg, tsl, cnts);
    moe_gemm_big<HD, BTD, false, 1><<<dim3(BTD / 128, CAPC / 256, NE), 512, 0, stream>>>(
        h2, W3, b3, h3, tidx, tg, tsl, cnts);
    moe_gemm_big<BTD, OD, false, 2><<<dim3(OD / 128, CAPC / 256, NE), 512, 0, stream>>>(
        h3, Wo, bo, yd, tidx, tg, tsl, cnts);
  }
  combine_ln<<<T_TOK, 256, 0, stream>>>(yd, lw, lb, out);
}

// Round 8
// 1076.376 us; speedup vs baseline: 1.5971x; 1.5971x over previous
//
#include <hip/hip_runtime.h>
#include <math.h>

#define T_TOK 2048
#define NE 64
#define KTOP 8
#define CAPC 512
#define DIN 768
#define HD 2048
#define BTD 256
#define OD 768

typedef short bf16x8 __attribute__((ext_vector_type(8)));
typedef float f32x4 __attribute__((ext_vector_type(4)));

__device__ __forceinline__ unsigned short f2bf(float f) {
  unsigned u = __float_as_uint(f);
  u += 0x7FFF + ((u >> 16) & 1);   // round-to-nearest-even
  return (unsigned short)(u >> 16);
}
__device__ __forceinline__ unsigned cvt2(float a, float b) {
  unsigned r;
  asm("v_cvt_pk_bf16_f32 %0, %1, %2" : "=v"(r) : "v"(a), "v"(b));
  return r;   // lo = bf16(a), hi = bf16(b)
}
__device__ __forceinline__ float gelu_exact(float v) {
  return 0.5f * v * (1.0f + erff(v * 0.7071067811865476f));
}
__device__ __forceinline__ void glds16(unsigned short* lds, const unsigned short* g) {
  __builtin_amdgcn_global_load_lds(
      (const __attribute__((address_space(1))) void*)g,
      (__attribute__((address_space(3))) void*)lds, 16, 0, 0);
}

// ---------------- x fp32 -> bf16 ---------------------------------------------------
__global__ __launch_bounds__(256) void cvt_x(const float* __restrict__ x,
                                             unsigned short* __restrict__ xb) {
  int i = blockIdx.x * 256 + threadIdx.x;
  float4 v = ((const float4*)x)[i];
  ushort4 o;
  o.x = f2bf(v.x); o.y = f2bf(v.y); o.z = f2bf(v.z); o.w = f2bf(v.w);
  ((ushort4*)xb)[i] = o;
}

// ---------------- router: fp32 logits, noisy top-8, softmax, gate/slot matrices ----
__global__ __launch_bounds__(256) void router_kernel(
    const float* __restrict__ x, const float* __restrict__ noise,
    const float* __restrict__ Wr, const float* __restrict__ br,
    const float* __restrict__ Wn, const float* __restrict__ bn,
    float* __restrict__ gate, int* __restrict__ slotm)
{
  __shared__ float xs[8][DIN];
  __shared__ float wrs[64][NE];
  __shared__ float wns[64][NE];
  const int tid = threadIdx.x;
  const int t0 = blockIdx.x * 8;
  for (int i = tid; i < 8 * (DIN / 4); i += 256) {
    int tt = i / (DIN / 4), c = i % (DIN / 4);
    ((float4*)xs[tt])[c] = ((const float4*)(x + (size_t)(t0 + tt) * DIN))[c];
  }
  const int lane = tid & 63;
  const int wv = tid >> 6;
  const int e = lane;
  const int ta = 2 * wv, tb = ta + 1;
  float ar0 = br[e], ar1 = ar0, an0 = bn[e], an1 = an0;
  for (int d0 = 0; d0 < DIN; d0 += 64) {
    __syncthreads();
    for (int i = tid; i < 64 * NE / 4; i += 256) {
      int dd = i >> 4, c4 = (i & 15) * 4;
      *(float4*)&wrs[dd][c4] = *(const float4*)&Wr[(size_t)(d0 + dd) * NE + c4];
      *(float4*)&wns[dd][c4] = *(const float4*)&Wn[(size_t)(d0 + dd) * NE + c4];
    }
    __syncthreads();
    #pragma unroll 8
    for (int dd = 0; dd < 64; dd++) {
      float wr = wrs[dd][e], wn = wns[dd][e];
      float xa = xs[ta][d0 + dd], xb = xs[tb][d0 + dd];
      ar0 = fmaf(xa, wr, ar0); ar1 = fmaf(xb, wr, ar1);
      an0 = fmaf(xa, wn, an0); an1 = fmaf(xb, wn, an1);
    }
  }
  #pragma unroll
  for (int s = 0; s < 2; s++) {
    int t = t0 + ta + s;
    float lr = s ? ar1 : ar0;
    float lnv = s ? an1 : an0;
    float sp = fmaxf(lnv, 0.f) + log1pf(expf(-fabsf(lnv)));   // softplus, overflow-safe
    float v = lr + noise[(size_t)t * NE + e] * sp;
    float cur = v;
    float topv[KTOP]; int topi[KTOP];
    #pragma unroll
    for (int j = 0; j < KTOP; j++) {
      float bv = cur; int bi = e;
      #pragma unroll
      for (int off = 32; off > 0; off >>= 1) {
        float ov = __shfl_xor(bv, off);
        int   oi = __shfl_xor(bi, off);
        if (ov > bv || (ov == bv && oi < bi)) { bv = ov; bi = oi; }
      }
      topv[j] = bv; topi[j] = bi;
      if (e == bi) cur = -INFINITY;
    }
    float mx = topv[0], se = 0.f, pv[KTOP];
    #pragma unroll
    for (int j = 0; j < KTOP; j++) { pv[j] = expf(topv[j] - mx); se += pv[j]; }
    float inv = 1.f / se;
    float g = 0.f; int sl = -1;
    #pragma unroll
    for (int j = 0; j < KTOP; j++) if (topi[j] == e) { g = pv[j] * inv; sl = j; }
    gate[(size_t)t * NE + e] = (sl >= 0) ? g : 0.f;
    slotm[(size_t)t * NE + e] = sl;
  }
}

// ---------------- dispatch: stable per-expert compaction (== stable argsort) -------
__global__ __launch_bounds__(256) void dispatch_kernel(
    const float* __restrict__ gate, const int* __restrict__ slotm,
    int* __restrict__ tok_idx, float* __restrict__ tok_g,
    int* __restrict__ tok_slot, int* __restrict__ counts)
{
  const int e = blockIdx.x;
  const int tid = threadIdx.x;
  __shared__ int wave_off[4];
  int base = 0;
  for (int t0 = 0; t0 < T_TOK; t0 += 256) {
    int t = t0 + tid;
    float g = gate[(size_t)t * NE + e];
    bool p = g > 0.f;
    unsigned long long m = __ballot(p);
    int wv = tid >> 6, lane = tid & 63;
    int pre = __popcll(m & ((1ull << lane) - 1ull));
    if (lane == 0) wave_off[wv] = __popcll(m);
    __syncthreads();
    int off = 0;
    for (int w = 0; w < wv; w++) off += wave_off[w];
    int tot = wave_off[0] + wave_off[1] + wave_off[2] + wave_off[3];
    if (p) {
      int pos = base + off + pre;
      if (pos < CAPC) {
        tok_idx[(size_t)e * CAPC + pos] = t;
        tok_g[(size_t)e * CAPC + pos] = g;
        tok_slot[(size_t)e * CAPC + pos] = slotm[(size_t)t * NE + e];
      }
    }
    base += tot;
    __syncthreads();
  }
  if (tid == 0) counts[e] = min(base, CAPC);
}

// ============== BIG expert GEMM: 256x128x32, role-split staging, XCD-grouped =======
// 1-D grid; decode: xcd = bid&7, e = (q/BPE)*8 + xcd -> all BPE blocks of an expert
// land on ONE XCD (n-panels consecutive => co-resident). The 16 n-panels' 512B row
// slices then cover W rows densely within one XCD's L2, and A is L2-cached once.
template<int KD, int NDT, bool AGATHER, int EPI, int NBN, int BPE>
__global__ __launch_bounds__(512, 1) void moe_gemm_big(
    const unsigned short* __restrict__ Abf, const float* __restrict__ Bw,
    const float* __restrict__ bias, void* __restrict__ Outp,
    const int* __restrict__ tok_idx, const float* __restrict__ tok_g,
    const int* __restrict__ tok_slot, const int* __restrict__ counts)
{
  constexpr int NK = KD / 32;
  static_assert(NK % 4 == 0 && NK >= 8, "NK must be multiple of 4");
  const int bid = blockIdx.x;
  const int xcd = bid & 7;
  const int q   = bid >> 3;
  const int e     = (q / BPE) * 8 + xcd;
  const int inner = q % BPE;
  const int n0 = (inner % NBN) * 128;
  const int m0 = (inner / NBN) * 256;
  const int cnt = counts[e];
  if (m0 >= cnt) return;
  const int tid = threadIdx.x;
  const int lane = tid & 63, wave = tid >> 6;

  __shared__ unsigned short AL[4][256][32];
  __shared__ unsigned short BL[4][128][40];
  __shared__ int   s_tok[256];
  __shared__ float s_g[256];
  __shared__ int   s_slot[256];

  if (EPI == 2 && tid < 256) {
    int gr = m0 + tid;
    if (gr < cnt) {
      s_tok[tid]  = tok_idx[(size_t)e * CAPC + gr];
      s_g[tid]    = tok_g[(size_t)e * CAPC + gr];
      s_slot[tid] = tok_slot[(size_t)e * CAPC + gr];
    }
  }

  const bool isB = wave < 4;
  const int  w4  = wave & 3;

  const float* bp = Bw + (size_t)e * KD * NDT + (size_t)(8 * w4) * NDT + n0 + 2 * lane;
  float2 breg[4][8];

  size_t a_off[4];
  if (!isB) {
    #pragma unroll
    for (int qq = 0; qq < 4; qq++) {
      int r  = w4 * 64 + qq * 16 + (lane >> 2);
      int cq = ((lane & 3) - (r >> 1)) & 3;
      size_t rowb;
      if (AGATHER) {
        int gr = m0 + r;
        int tk = (gr < cnt) ? tok_idx[(size_t)e * CAPC + gr] : 0;
        rowb = (size_t)tk * KD;
      } else {
        rowb = ((size_t)e * CAPC + m0 + r) * KD;
      }
      a_off[qq] = rowb + 8 * cq;
    }
  }

  auto stageA = [&](int t, int s) {
    #pragma unroll
    for (int qq = 0; qq < 4; qq++)
      glds16(&AL[s][0][0] + w4 * 2048 + qq * 512, Abf + a_off[qq] + (size_t)t * 32);
  };
  auto loadB = [&](int t, int p) {
    const float* pb = bp + (size_t)t * 32 * NDT;
    #pragma unroll
    for (int j = 0; j < 8; j++) breg[p][j] = *(const float2*)(pb + (size_t)j * NDT);
  };
  auto writeB = [&](int s, int p) {
    uint4 rx, ry;
    rx.x = cvt2(breg[p][0].x, breg[p][1].x); rx.y = cvt2(breg[p][2].x, breg[p][3].x);
    rx.z = cvt2(breg[p][4].x, breg[p][5].x); rx.w = cvt2(breg[p][6].x, breg[p][7].x);
    ry.x = cvt2(breg[p][0].y, breg[p][1].y); ry.y = cvt2(breg[p][2].y, breg[p][3].y);
    ry.z = cvt2(breg[p][4].y, breg[p][5].y); ry.w = cvt2(breg[p][6].y, breg[p][7].y);
    *(uint4*)&BL[s][2 * lane][8 * w4]     = rx;
    *(uint4*)&BL[s][2 * lane + 1][8 * w4] = ry;
  };

  const int wm = (wave >> 1) * 64;
  const int wn = (wave & 1) * 64;
  const int li = lane & 15, lg = lane >> 4;
  const int kxa = 8 * ((lg + ((li >> 1) & 3)) & 3);

  f32x4 acc[4][4];
  #pragma unroll
  for (int i = 0; i < 4; i++)
    #pragma unroll
    for (int j = 0; j < 4; j++) acc[i][j] = (f32x4){0.f, 0.f, 0.f, 0.f};

  auto step = [&](int s) {
    bf16x8 afr[4], bfr[4];
    #pragma unroll
    for (int mi = 0; mi < 4; mi++)
      afr[mi] = *(const bf16x8*)&AL[s][wm + mi * 16 + li][kxa];
    #pragma unroll
    for (int ni = 0; ni < 4; ni++)
      bfr[ni] = *(const bf16x8*)&BL[s][wn + ni * 16 + li][lg * 8];
    __builtin_amdgcn_s_setprio(1);
    #pragma unroll
    for (int mi = 0; mi < 4; mi++)
      #pragma unroll
      for (int ni = 0; ni < 4; ni++)
        acc[mi][ni] = __builtin_amdgcn_mfma_f32_16x16x32_bf16(afr[mi], bfr[ni], acc[mi][ni], 0, 0, 0);
    __builtin_amdgcn_s_setprio(0);
  };

  if (isB) {
    loadB(0, 0); loadB(1, 1); loadB(2, 2);
    asm volatile("s_waitcnt vmcnt(16)" ::: "memory");
    writeB(0, 0);
    asm volatile("s_waitcnt lgkmcnt(0)" ::: "memory");
  } else {
    stageA(0, 0); stageA(1, 1); stageA(2, 2);
    asm volatile("s_waitcnt vmcnt(8)" ::: "memory");
  }
  __builtin_amdgcn_s_barrier();

  #define SUBITER(p)                                                        \
    do {                                                                    \
      const int jj = jb + (p);                                              \
      if (isB) loadB(min(jj + 3, NK - 1), ((p) + 3) & 3);                   \
      else     stageA(min(jj + 3, NK - 1), ((p) + 3) & 3);                  \
      step(p);                                                              \
      if (isB) {                                                            \
        asm volatile("s_waitcnt vmcnt(16)" ::: "memory");                   \
        writeB(((p) + 1) & 3, ((p) + 1) & 3);                               \
        asm volatile("s_waitcnt lgkmcnt(0)" ::: "memory");                  \
      } else {                                                              \
        asm volatile("s_waitcnt vmcnt(8)" ::: "memory");                    \
      }                                                                     \
      __builtin_amdgcn_s_barrier();                                        \
    } while (0)

  for (int jb = 0; jb < NK; jb += 4) {
    SUBITER(0); SUBITER(1); SUBITER(2); SUBITER(3);
  }
  #undef SUBITER
  asm volatile("s_waitcnt vmcnt(0)" ::: "memory");

  const float* bpb = bias + (size_t)e * NDT;
  #pragma unroll
  for (int mi = 0; mi < 4; mi++) {
    #pragma unroll
    for (int ni = 0; ni < 4; ni++) {
      const int ncol = n0 + wn + ni * 16 + li;
      const float bb = bpb[ncol];
      #pragma unroll
      for (int qq = 0; qq < 4; qq++) {
        const int r = wm + mi * 16 + lg * 4 + qq;
        const int gr = m0 + r;
        if (gr < cnt) {
          float v = acc[mi][ni][qq] + bb;
          if (EPI == 0) {
            v = gelu_exact(v);
            ((unsigned short*)Outp)[((size_t)e * CAPC + gr) * NDT + ncol] = f2bf(v);
          } else if (EPI == 1) {
            ((unsigned short*)Outp)[((size_t)e * CAPC + gr) * NDT + ncol] = f2bf(v);
          } else {
            ((float*)Outp)[((size_t)s_tok[r] * KTOP + s_slot[r]) * OD + ncol] = v * s_g[r];
          }
        }
      }
    }
  }
}

// ---------------- 128x128x32 expert GEMM (r4) + XCD-grouped decode, for G3/G4 ------
template<int KD, int ND, bool AGATHER, int EPI, int NBN, int BPE>
__global__ __launch_bounds__(256, 2) void moe_gemm(
    const unsigned short* __restrict__ Abf, const float* __restrict__ Bw,
    const float* __restrict__ bias, void* __restrict__ Outp,
    const int* __restrict__ tok_idx, const float* __restrict__ tok_g,
    const int* __restrict__ tok_slot, const int* __restrict__ counts)
{
  constexpr int NK = KD / 32;
  static_assert(NK % 4 == 0 && NK >= 8, "NK must be multiple of 4");
  const int bid = blockIdx.x;
  const int xcd = bid & 7;
  const int q   = bid >> 3;
  const int e     = (q / BPE) * 8 + xcd;
  const int inner = q % BPE;
  const int n0 = (inner % NBN) * 128;
  const int m0 = (inner / NBN) * 128;
  const int cnt = counts[e];
  if (m0 >= cnt) return;
  const int tid = threadIdx.x;

  __shared__ unsigned short AL[4][128][32];
  __shared__ unsigned short BL[4][128][40];
  __shared__ int   s_tok[128];
  __shared__ float s_g[128];
  __shared__ int   s_slot[128];

  if (EPI == 2 && tid < 128) {
    int gr = m0 + tid;
    if (gr < cnt) {
      s_tok[tid]  = tok_idx[(size_t)e * CAPC + gr];
      s_g[tid]    = tok_g[(size_t)e * CAPC + gr];
      s_slot[tid] = tok_slot[(size_t)e * CAPC + gr];
    }
  }

  const int ar0 = tid >> 2;
  const int ac  = 8 * (((tid & 3) - (tid >> 3)) & 3);
  size_t arow0, arow1;
  if (AGATHER) {
    int g0 = m0 + ar0, g1 = m0 + 64 + ar0;
    int t0i = (g0 < cnt) ? tok_idx[(size_t)e * CAPC + g0] : 0;
    int t1i = (g1 < cnt) ? tok_idx[(size_t)e * CAPC + g1] : 0;
    arow0 = (size_t)t0i * KD; arow1 = (size_t)t1i * KD;
  } else {
    arow0 = ((size_t)e * CAPC + m0 + ar0) * KD;
    arow1 = arow0 + (size_t)64 * KD;
  }
  const unsigned short* ap0 = Abf + arow0 + ac;
  const unsigned short* ap1 = Abf + arow1 + ac;
  const int awb = (tid & 192) * 8;

  const int l = tid & 63, w = tid >> 6;
  const float* bp = Bw + (size_t)e * KD * ND + (size_t)(8 * w) * ND + n0 + 2 * l;

  float2 breg[4][8];

  auto stageA = [&](int t, int s) {
    glds16(&AL[s][0][0] + awb,        ap0 + t * 32);
    glds16(&AL[s][0][0] + 2048 + awb, ap1 + t * 32);
  };
  auto loadB = [&](int t, int p) {
    const float* pb = bp + (size_t)t * 32 * ND;
    #pragma unroll
    for (int j = 0; j < 8; j++) breg[p][j] = *(const float2*)(pb + (size_t)j * ND);
  };
  auto writeB = [&](int s, int p) {
    uint4 rx, ry;
    rx.x = cvt2(breg[p][0].x, breg[p][1].x); rx.y = cvt2(breg[p][2].x, breg[p][3].x);
    rx.z = cvt2(breg[p][4].x, breg[p][5].x); rx.w = cvt2(breg[p][6].x, breg[p][7].x);
    ry.x = cvt2(breg[p][0].y, breg[p][1].y); ry.y = cvt2(breg[p][2].y, breg[p][3].y);
    ry.z = cvt2(breg[p][4].y, breg[p][5].y); ry.w = cvt2(breg[p][6].y, breg[p][7].y);
    *(uint4*)&BL[s][2 * l][8 * w]     = rx;
    *(uint4*)&BL[s][2 * l + 1][8 * w] = ry;
  };

  const int lane = tid & 63, wv = tid >> 6;
  const int wm = (wv >> 1) * 64, wn = (wv & 1) * 64;
  const int li = lane & 15, lg = lane >> 4;
  const int kxa = 8 * ((lg + ((li >> 1) & 3)) & 3);

  f32x4 acc[4][4];
  #pragma unroll
  for (int i = 0; i < 4; i++)
    #pragma unroll
    for (int j = 0; j < 4; j++) acc[i][j] = (f32x4){0.f, 0.f, 0.f, 0.f};

  auto step = [&](int s) {
    bf16x8 afr[4], bfr[4];
    #pragma unroll
    for (int mi = 0; mi < 4; mi++)
      afr[mi] = *(const bf16x8*)&AL[s][wm + mi * 16 + li][kxa];
    #pragma unroll
    for (int ni = 0; ni < 4; ni++)
      bfr[ni] = *(const bf16x8*)&BL[s][wn + ni * 16 + li][lg * 8];
    __builtin_amdgcn_s_setprio(1);
    #pragma unroll
    for (int mi = 0; mi < 4; mi++)
      #pragma unroll
      for (int ni = 0; ni < 4; ni++)
        acc[mi][ni] = __builtin_amdgcn_mfma_f32_16x16x32_bf16(afr[mi], bfr[ni], acc[mi][ni], 0, 0, 0);
    __builtin_amdgcn_s_setprio(0);
  };

  loadB(0, 0);
  stageA(0, 0); loadB(1, 1);
  stageA(1, 1); loadB(2, 2);
  stageA(2, 2); loadB(3, 3);
  asm volatile("s_waitcnt vmcnt(28)" ::: "memory");
  writeB(0, 0);
  asm volatile("s_waitcnt lgkmcnt(0)" ::: "memory");
  __builtin_amdgcn_s_barrier();

  #define SUBITER(p)                                                        \
    do {                                                                    \
      const int jj = jb + (p);                                              \
      stageA(min(jj + 3, NK - 1), ((p) + 3) & 3);                           \
      loadB(min(jj + 4, NK - 1), (p));                                      \
      step(p);                                                              \
      asm volatile("s_waitcnt vmcnt(28)" ::: "memory");                     \
      writeB(((p) + 1) & 3, ((p) + 1) & 3);                                 \
      asm volatile("s_waitcnt lgkmcnt(0)" ::: "memory");                    \
      __builtin_amdgcn_s_barrier();                                         \
    } while (0)

  for (int jb = 0; jb < NK; jb += 4) {
    SUBITER(0); SUBITER(1); SUBITER(2); SUBITER(3);
  }
  #undef SUBITER
  asm volatile("s_waitcnt vmcnt(0)" ::: "memory");

  const float* bpb = bias + (size_t)e * ND;
  #pragma unroll
  for (int mi = 0; mi < 4; mi++) {
    #pragma unroll
    for (int ni = 0; ni < 4; ni++) {
      const int ncol = n0 + wn + ni * 16 + li;
      const float bb = bpb[ncol];
      #pragma unroll
      for (int qq = 0; qq < 4; qq++) {
        const int r = wm + mi * 16 + lg * 4 + qq;
        const int gr = m0 + r;
        if (gr < cnt) {
          float v = acc[mi][ni][qq] + bb;
          if (EPI == 0) {
            v = gelu_exact(v);
            ((unsigned short*)Outp)[((size_t)e * CAPC + gr) * ND + ncol] = f2bf(v);
          } else if (EPI == 1) {
            ((unsigned short*)Outp)[((size_t)e * CAPC + gr) * ND + ncol] = f2bf(v);
          } else {
            ((float*)Outp)[((size_t)s_tok[r] * KTOP + s_slot[r]) * OD + ncol] = v * s_g[r];
          }
        }
      }
    }
  }
}

// ---------------- combine 8 slots + LayerNorm -------------------------------------
__global__ __launch_bounds__(256) void combine_ln(
    const float* __restrict__ yd, const float* __restrict__ lw,
    const float* __restrict__ lb, float* __restrict__ out)
{
  const int t = blockIdx.x, tid = threadIdx.x;
  float v[3];
  #pragma unroll
  for (int i = 0; i < 3; i++) {
    const int c = tid + 256 * i;
    float s = 0.f;
    #pragma unroll
    for (int j = 0; j < KTOP; j++) s += yd[((size_t)t * KTOP + j) * OD + c];
    v[i] = s;
  }
  float s1 = v[0] + v[1] + v[2];
  float s2 = v[0] * v[0] + v[1] * v[1] + v[2] * v[2];
  #pragma unroll
  for (int off = 32; off > 0; off >>= 1) {
    s1 += __shfl_xor(s1, off);
    s2 += __shfl_xor(s2, off);
  }
  __shared__ float as1[4], as2[4];
  const int lane = tid & 63, wv = tid >> 6;
  if (lane == 0) { as1[wv] = s1; as2[wv] = s2; }
  __syncthreads();
  s1 = as1[0] + as1[1] + as1[2] + as1[3];
  s2 = as2[0] + as2[1] + as2[2] + as2[3];
  const float mu = s1 * (1.f / OD);
  const float var = s2 * (1.f / OD) - mu * mu;
  const float rstd = rsqrtf(var + 1e-5f);
  #pragma unroll
  for (int i = 0; i < 3; i++) {
    const int c = tid + 256 * i;
    out[(size_t)t * OD + c] = (v[i] - mu) * rstd * lw[c] + lb[c];
  }
}

extern "C" void kernel_launch(void* const* d_in, const int* in_sizes, int n_in,
                              void* d_out, int out_size, void* d_ws, size_t ws_size,
                              hipStream_t stream) {
  const float* x     = (const float*)d_in[0];
  const float* noise = (const float*)d_in[1];
  const float* Wr    = (const float*)d_in[2];
  const float* br    = (const float*)d_in[3];
  const float* Wn    = (const float*)d_in[4];
  const float* bn    = (const float*)d_in[5];
  const float* W1    = (const float*)d_in[6];
  const float* b1    = (const float*)d_in[7];
  const float* W2    = (const float*)d_in[8];
  const float* b2    = (const float*)d_in[9];
  const float* W3    = (const float*)d_in[10];
  const float* b3    = (const float*)d_in[11];
  const float* Wo    = (const float*)d_in[12];
  const float* bo    = (const float*)d_in[13];
  const float* lw    = (const float*)d_in[14];
  const float* lb    = (const float*)d_in[15];
  float* out = (float*)d_out;

  char* ws = (char*)d_ws;
  constexpr size_t OFF_GATE = 0;
  constexpr size_t OFF_SLOT = OFF_GATE + (size_t)T_TOK * NE * 4;
  constexpr size_t OFF_TIDX = OFF_SLOT + (size_t)T_TOK * NE * 4;
  constexpr size_t OFF_TG   = OFF_TIDX + (size_t)NE * CAPC * 4;
  constexpr size_t OFF_TSL  = OFF_TG + (size_t)NE * CAPC * 4;
  constexpr size_t OFF_CNT  = OFF_TSL + (size_t)NE * CAPC * 4;
  constexpr size_t OFF_YD   = ((OFF_CNT + NE * 4) + 255) & ~(size_t)255;
  constexpr size_t SZ_YD    = (size_t)T_TOK * KTOP * OD * 4;
  constexpr size_t OFF_H1   = OFF_YD + SZ_YD;
  constexpr size_t OFF_H2   = OFF_H1 + (size_t)NE * CAPC * HD * 2;
  constexpr size_t OFF_H3   = OFF_H2 + (size_t)NE * CAPC * HD * 2;
  constexpr size_t OFF_XBF  = OFF_H3 + (size_t)NE * CAPC * BTD * 2;

  float* gate = (float*)(ws + OFF_GATE);
  int*   slot = (int*)(ws + OFF_SLOT);
  int*   tidx = (int*)(ws + OFF_TIDX);
  float* tg   = (float*)(ws + OFF_TG);
  int*   tsl  = (int*)(ws + OFF_TSL);
  int*   cnts = (int*)(ws + OFF_CNT);
  float* yd   = (float*)(ws + OFF_YD);
  unsigned short* h1  = (unsigned short*)(ws + OFF_H1);
  unsigned short* h2  = (unsigned short*)(ws + OFF_H2);
  unsigned short* h3  = (unsigned short*)(ws + OFF_H3);
  unsigned short* xbf = (unsigned short*)(ws + OFF_XBF);

  hipMemsetAsync(yd, 0, SZ_YD, stream);
  cvt_x<<<T_TOK * DIN / 4 / 256, 256, 0, stream>>>(x, xbf);
  router_kernel<<<T_TOK / 8, 256, 0, stream>>>(x, noise, Wr, br, Wn, bn, gate, slot);
  dispatch_kernel<<<NE, 256, 0, stream>>>(gate, slot, tidx, tg, tsl, cnts);
  // G1: 16 n-panels x 2 m x 64 e -> BPE=32, 2048 blocks, XCD-grouped
  moe_gemm_big<DIN, HD, true, 0, 16, 32><<<2048, 512, 0, stream>>>(
      xbf, W1, b1, h1, tidx, tg, tsl, cnts);
  // G2: same geometry
  moe_gemm_big<HD, HD, false, 0, 16, 32><<<2048, 512, 0, stream>>>(
      h1, W2, b2, h2, tidx, tg, tsl, cnts);
  // G3: 2 n x 4 m x 64 e -> BPE=8, 512 blocks
  moe_gemm<HD, BTD, false, 1, 2, 8><<<512, 256, 0, stream>>>(
      h2, W3, b3, h3, tidx, tg, tsl, cnts);
  // G4: 6 n x 4 m x 64 e -> BPE=24, 1536 blocks
  moe_gemm<BTD, OD, false, 2, 6, 24><<<1536, 256, 0, stream>>>(
      h3, Wo, bo, yd, tidx, tg, tsl, cnts);
  combine_ln<<<T_TOK, 256, 0, stream>>>(yd, lw, lb, out);
}

// Round 9
// 1051.396 us; speedup vs baseline: 1.6350x; 1.0238x over previous
//
#include <hip/hip_runtime.h>
#include <math.h>

#define T_TOK 2048
#define NE 64
#define KTOP 8
#define CAPC 512
#define DIN 768
#define HD 2048
#define BTD 256
#define OD 768

typedef short bf16x8 __attribute__((ext_vector_type(8)));
typedef float f32x4 __attribute__((ext_vector_type(4)));

__device__ __forceinline__ unsigned short f2bf(float f) {
  unsigned u = __float_as_uint(f);
  u += 0x7FFF + ((u >> 16) & 1);   // round-to-nearest-even
  return (unsigned short)(u >> 16);
}
__device__ __forceinline__ unsigned cvt2(float a, float b) {
  unsigned r;
  asm("v_cvt_pk_bf16_f32 %0, %1, %2" : "=v"(r) : "v"(a), "v"(b));
  return r;   // lo = bf16(a), hi = bf16(b)
}
__device__ __forceinline__ float gelu_exact(float v) {
  return 0.5f * v * (1.0f + erff(v * 0.7071067811865476f));
}
__device__ __forceinline__ void glds16(unsigned short* lds, const unsigned short* g) {
  __builtin_amdgcn_global_load_lds(
      (const __attribute__((address_space(1))) void*)g,
      (__attribute__((address_space(3))) void*)lds, 16, 0, 0);
}

// ---------------- x fp32 -> bf16 ---------------------------------------------------
__global__ __launch_bounds__(256) void cvt_x(const float* __restrict__ x,
                                             unsigned short* __restrict__ xb) {
  int i = blockIdx.x * 256 + threadIdx.x;
  float4 v = ((const float4*)x)[i];
  ushort4 o;
  o.x = f2bf(v.x); o.y = f2bf(v.y); o.z = f2bf(v.z); o.w = f2bf(v.w);
  ((ushort4*)xb)[i] = o;
}

// ---------------- router: fp32 logits, noisy top-8, softmax, gate/slot matrices ----
__global__ __launch_bounds__(256) void router_kernel(
    const float* __restrict__ x, const float* __restrict__ noise,
    const float* __restrict__ Wr, const float* __restrict__ br,
    const float* __restrict__ Wn, const float* __restrict__ bn,
    float* __restrict__ gate, int* __restrict__ slotm)
{
  __shared__ float xs[8][DIN];
  __shared__ float wrs[64][NE];
  __shared__ float wns[64][NE];
  const int tid = threadIdx.x;
  const int t0 = blockIdx.x * 8;
  for (int i = tid; i < 8 * (DIN / 4); i += 256) {
    int tt = i / (DIN / 4), c = i % (DIN / 4);
    ((float4*)xs[tt])[c] = ((const float4*)(x + (size_t)(t0 + tt) * DIN))[c];
  }
  const int lane = tid & 63;
  const int wv = tid >> 6;
  const int e = lane;
  const int ta = 2 * wv, tb = ta + 1;
  float ar0 = br[e], ar1 = ar0, an0 = bn[e], an1 = an0;
  for (int d0 = 0; d0 < DIN; d0 += 64) {
    __syncthreads();
    for (int i = tid; i < 64 * NE / 4; i += 256) {
      int dd = i >> 4, c4 = (i & 15) * 4;
      *(float4*)&wrs[dd][c4] = *(const float4*)&Wr[(size_t)(d0 + dd) * NE + c4];
      *(float4*)&wns[dd][c4] = *(const float4*)&Wn[(size_t)(d0 + dd) * NE + c4];
    }
    __syncthreads();
    #pragma unroll 8
    for (int dd = 0; dd < 64; dd++) {
      float wr = wrs[dd][e], wn = wns[dd][e];
      float xa = xs[ta][d0 + dd], xb = xs[tb][d0 + dd];
      ar0 = fmaf(xa, wr, ar0); ar1 = fmaf(xb, wr, ar1);
      an0 = fmaf(xa, wn, an0); an1 = fmaf(xb, wn, an1);
    }
  }
  #pragma unroll
  for (int s = 0; s < 2; s++) {
    int t = t0 + ta + s;
    float lr = s ? ar1 : ar0;
    float lnv = s ? an1 : an0;
    float sp = fmaxf(lnv, 0.f) + log1pf(expf(-fabsf(lnv)));   // softplus, overflow-safe
    float v = lr + noise[(size_t)t * NE + e] * sp;
    float cur = v;
    float topv[KTOP]; int topi[KTOP];
    #pragma unroll
    for (int j = 0; j < KTOP; j++) {
      float bv = cur; int bi = e;
      #pragma unroll
      for (int off = 32; off > 0; off >>= 1) {
        float ov = __shfl_xor(bv, off);
        int   oi = __shfl_xor(bi, off);
        if (ov > bv || (ov == bv && oi < bi)) { bv = ov; bi = oi; }
      }
      topv[j] = bv; topi[j] = bi;
      if (e == bi) cur = -INFINITY;
    }
    float mx = topv[0], se = 0.f, pv[KTOP];
    #pragma unroll
    for (int j = 0; j < KTOP; j++) { pv[j] = expf(topv[j] - mx); se += pv[j]; }
    float inv = 1.f / se;
    float g = 0.f; int sl = -1;
    #pragma unroll
    for (int j = 0; j < KTOP; j++) if (topi[j] == e) { g = pv[j] * inv; sl = j; }
    gate[(size_t)t * NE + e] = (sl >= 0) ? g : 0.f;
    slotm[(size_t)t * NE + e] = sl;
  }
}

// ---------------- dispatch: stable per-expert compaction (== stable argsort) -------
__global__ __launch_bounds__(256) void dispatch_kernel(
    const float* __restrict__ gate, const int* __restrict__ slotm,
    int* __restrict__ tok_idx, float* __restrict__ tok_g,
    int* __restrict__ tok_slot, int* __restrict__ counts)
{
  const int e = blockIdx.x;
  const int tid = threadIdx.x;
  __shared__ int wave_off[4];
  int base = 0;
  for (int t0 = 0; t0 < T_TOK; t0 += 256) {
    int t = t0 + tid;
    float g = gate[(size_t)t * NE + e];
    bool p = g > 0.f;
    unsigned long long m = __ballot(p);
    int wv = tid >> 6, lane = tid & 63;
    int pre = __popcll(m & ((1ull << lane) - 1ull));
    if (lane == 0) wave_off[wv] = __popcll(m);
    __syncthreads();
    int off = 0;
    for (int w = 0; w < wv; w++) off += wave_off[w];
    int tot = wave_off[0] + wave_off[1] + wave_off[2] + wave_off[3];
    if (p) {
      int pos = base + off + pre;
      if (pos < CAPC) {
        tok_idx[(size_t)e * CAPC + pos] = t;
        tok_g[(size_t)e * CAPC + pos] = g;
        tok_slot[(size_t)e * CAPC + pos] = slotm[(size_t)t * NE + e];
      }
    }
    base += tot;
    __syncthreads();
  }
  if (tid == 0) counts[e] = min(base, CAPC);
}

// ============== BIG expert GEMM: 256x128x32, role-split, XCD-grouped, 2 blocks/CU ==
// LDS: A 3 rotating buffers (48 KB), B 2 rotating buffers (20 KB) -> ~70 KB total
// => 2 blocks/CU co-resident; when one block waits at its barrier the other issues.
// B register pipeline stays 3-deep (breg[4] slots, compile-time indices via unroll-4).
template<int KD, int NDT, bool AGATHER, int EPI, int NBN, int BPE>
__global__ __launch_bounds__(512, 2) void moe_gemm_big(
    const unsigned short* __restrict__ Abf, const float* __restrict__ Bw,
    const float* __restrict__ bias, void* __restrict__ Outp,
    const int* __restrict__ tok_idx, const float* __restrict__ tok_g,
    const int* __restrict__ tok_slot, const int* __restrict__ counts)
{
  constexpr int NK = KD / 32;
  static_assert(NK % 4 == 0 && NK >= 8, "NK must be multiple of 4");
  const int bid = blockIdx.x;
  const int xcd = bid & 7;
  const int q   = bid >> 3;
  const int e     = (q / BPE) * 8 + xcd;
  const int inner = q % BPE;
  const int n0 = (inner % NBN) * 128;
  const int m0 = (inner / NBN) * 256;
  const int cnt = counts[e];
  if (m0 >= cnt) return;
  const int tid = threadIdx.x;
  const int lane = tid & 63, wave = tid >> 6;

  __shared__ unsigned short AL[3][256][32];   // 48 KB
  __shared__ unsigned short BL[2][128][40];   // 20 KB
  __shared__ int   s_tok[EPI == 2 ? 256 : 1];
  __shared__ float s_g[EPI == 2 ? 256 : 1];
  __shared__ int   s_slot[EPI == 2 ? 256 : 1];

  if (EPI == 2 && tid < 256) {
    int gr = m0 + tid;
    if (gr < cnt) {
      s_tok[tid]  = tok_idx[(size_t)e * CAPC + gr];
      s_g[tid]    = tok_g[(size_t)e * CAPC + gr];
      s_slot[tid] = tok_slot[(size_t)e * CAPC + gr];
    }
  }

  const bool isB = wave < 4;
  const int  w4  = wave & 3;

  // ---- B staging (waves 0-3): lane covers cols n0+2*lane..+1, k rows 8*w4..+7 ----
  const float* bp = Bw + (size_t)e * KD * NDT + (size_t)(8 * w4) * NDT + n0 + 2 * lane;
  float2 breg[4][8];

  // ---- A staging (waves 4-7): 4 glds16/thread, chunk-permuted source ----
  size_t a_off[4];
  if (!isB) {
    #pragma unroll
    for (int qq = 0; qq < 4; qq++) {
      int r  = w4 * 64 + qq * 16 + (lane >> 2);
      int cq = ((lane & 3) - (r >> 1)) & 3;
      size_t rowb;
      if (AGATHER) {
        int gr = m0 + r;
        int tk = (gr < cnt) ? tok_idx[(size_t)e * CAPC + gr] : 0;
        rowb = (size_t)tk * KD;
      } else {
        rowb = ((size_t)e * CAPC + m0 + r) * KD;
      }
      a_off[qq] = rowb + 8 * cq;
    }
  }

  auto stageA = [&](int t, unsigned short* Abuf) {
    #pragma unroll
    for (int qq = 0; qq < 4; qq++)
      glds16(Abuf + w4 * 2048 + qq * 512, Abf + a_off[qq] + (size_t)t * 32);
  };
  auto loadB = [&](int t, int p) {
    const float* pb = bp + (size_t)t * 32 * NDT;
    #pragma unroll
    for (int j = 0; j < 8; j++) breg[p][j] = *(const float2*)(pb + (size_t)j * NDT);
  };
  auto writeB = [&](unsigned short* Bbuf, int p) {
    uint4 rx, ry;
    rx.x = cvt2(breg[p][0].x, breg[p][1].x); rx.y = cvt2(breg[p][2].x, breg[p][3].x);
    rx.z = cvt2(breg[p][4].x, breg[p][5].x); rx.w = cvt2(breg[p][6].x, breg[p][7].x);
    ry.x = cvt2(breg[p][0].y, breg[p][1].y); ry.y = cvt2(breg[p][2].y, breg[p][3].y);
    ry.z = cvt2(breg[p][4].y, breg[p][5].y); ry.w = cvt2(breg[p][6].y, breg[p][7].y);
    *(uint4*)(Bbuf + (2 * lane) * 40 + 8 * w4)     = rx;
    *(uint4*)(Bbuf + (2 * lane + 1) * 40 + 8 * w4) = ry;
  };

  const int wm = (wave >> 1) * 64;
  const int wn = (wave & 1) * 64;
  const int li = lane & 15, lg = lane >> 4;
  const int kxa = 8 * ((lg + ((li >> 1) & 3)) & 3);

  f32x4 acc[4][4];
  #pragma unroll
  for (int i = 0; i < 4; i++)
    #pragma unroll
    for (int j = 0; j < 4; j++) acc[i][j] = (f32x4){0.f, 0.f, 0.f, 0.f};

  auto step = [&](const unsigned short* Abuf, const unsigned short* Bbuf) {
    bf16x8 afr[4], bfr[4];
    #pragma unroll
    for (int mi = 0; mi < 4; mi++)
      afr[mi] = *(const bf16x8*)(Abuf + (wm + mi * 16 + li) * 32 + kxa);
    #pragma unroll
    for (int ni = 0; ni < 4; ni++)
      bfr[ni] = *(const bf16x8*)(Bbuf + (wn + ni * 16 + li) * 40 + lg * 8);
    __builtin_amdgcn_s_setprio(1);
    #pragma unroll
    for (int mi = 0; mi < 4; mi++)
      #pragma unroll
      for (int ni = 0; ni < 4; ni++)
        acc[mi][ni] = __builtin_amdgcn_mfma_f32_16x16x32_bf16(afr[mi], bfr[ni], acc[mi][ni], 0, 0, 0);
    __builtin_amdgcn_s_setprio(0);
  };

  unsigned short *A0 = &AL[0][0][0], *A1 = &AL[1][0][0], *A2 = &AL[2][0][0];
  unsigned short *B0 = &BL[0][0][0], *B1 = &BL[1][0][0];

  // ---- prologue ----
  if (isB) {
    loadB(0, 0); loadB(1, 1); loadB(2, 2);                 // 24 vm out
    asm volatile("s_waitcnt vmcnt(16)" ::: "memory");      // loadB(0) retired
    writeB(B0, 0);
    asm volatile("s_waitcnt lgkmcnt(0)" ::: "memory");
  } else {
    stageA(0, A0); stageA(1, A1);                          // 8 vm out
    asm volatile("s_waitcnt vmcnt(4)" ::: "memory");       // stageA(0) landed
  }
  __builtin_amdgcn_s_barrier();

  // steady sub-iter j (slot p = j&3):
  //   B-waves: issue loadB(j+3) -> {j+1,j+2,j+3}=24 out; after step vmcnt(16)
  //            retires loadB(j+1) -> writeB into B1; lgkm0
  //   A-waves: issue stageA(j+2 -> A2) -> {j+1,j+2}=8 out; after step vmcnt(4)
  //            retires stageA(j+1) (-> A1 complete)
  //   barrier publishes tile j+1 (A1,B1); rotate pointers.
  #define SUBITER(p)                                                        \
    do {                                                                    \
      const int jj = jb + (p);                                              \
      if (isB) loadB(min(jj + 3, NK - 1), ((p) + 3) & 3);                   \
      else     stageA(min(jj + 2, NK - 1), A2);                             \
      step(A0, B0);                                                         \
      if (isB) {                                                            \
        asm volatile("s_waitcnt vmcnt(16)" ::: "memory");                   \
        writeB(B1, ((p) + 1) & 3);                                          \
        asm volatile("s_waitcnt lgkmcnt(0)" ::: "memory");                  \
      } else {                                                              \
        asm volatile("s_waitcnt vmcnt(4)" ::: "memory");                    \
      }                                                                     \
      __builtin_amdgcn_s_barrier();                                         \
      unsigned short* ta = A0; A0 = A1; A1 = A2; A2 = ta;                   \
      unsigned short* tb = B0; B0 = B1; B1 = tb;                            \
    } while (0)

  for (int jb = 0; jb < NK; jb += 4) {
    SUBITER(0); SUBITER(1); SUBITER(2); SUBITER(3);
  }
  #undef SUBITER
  asm volatile("s_waitcnt vmcnt(0)" ::: "memory");   // drain gload_lds before WG exit

  const float* bpb = bias + (size_t)e * NDT;
  #pragma unroll
  for (int mi = 0; mi < 4; mi++) {
    #pragma unroll
    for (int ni = 0; ni < 4; ni++) {
      const int ncol = n0 + wn + ni * 16 + li;
      const float bb = bpb[ncol];
      #pragma unroll
      for (int qq = 0; qq < 4; qq++) {
        const int r = wm + mi * 16 + lg * 4 + qq;
        const int gr = m0 + r;
        if (gr < cnt) {
          float v = acc[mi][ni][qq] + bb;
          if (EPI == 0) {
            v = gelu_exact(v);
            ((unsigned short*)Outp)[((size_t)e * CAPC + gr) * NDT + ncol] = f2bf(v);
          } else if (EPI == 1) {
            ((unsigned short*)Outp)[((size_t)e * CAPC + gr) * NDT + ncol] = f2bf(v);
          } else {
            ((float*)Outp)[((size_t)s_tok[r] * KTOP + s_slot[r]) * OD + ncol] = v * s_g[r];
          }
        }
      }
    }
  }
}

// ---------------- 128x128x32 expert GEMM + XCD-grouped decode, for G3/G4 -----------
template<int KD, int ND, bool AGATHER, int EPI, int NBN, int BPE>
__global__ __launch_bounds__(256, 2) void moe_gemm(
    const unsigned short* __restrict__ Abf, const float* __restrict__ Bw,
    const float* __restrict__ bias, void* __restrict__ Outp,
    const int* __restrict__ tok_idx, const float* __restrict__ tok_g,
    const int* __restrict__ tok_slot, const int* __restrict__ counts)
{
  constexpr int NK = KD / 32;
  static_assert(NK % 4 == 0 && NK >= 8, "NK must be multiple of 4");
  const int bid = blockIdx.x;
  const int xcd = bid & 7;
  const int q   = bid >> 3;
  const int e     = (q / BPE) * 8 + xcd;
  const int inner = q % BPE;
  const int n0 = (inner % NBN) * 128;
  const int m0 = (inner / NBN) * 128;
  const int cnt = counts[e];
  if (m0 >= cnt) return;
  const int tid = threadIdx.x;

  __shared__ unsigned short AL[4][128][32];
  __shared__ unsigned short BL[4][128][40];
  __shared__ int   s_tok[128];
  __shared__ float s_g[128];
  __shared__ int   s_slot[128];

  if (EPI == 2 && tid < 128) {
    int gr = m0 + tid;
    if (gr < cnt) {
      s_tok[tid]  = tok_idx[(size_t)e * CAPC + gr];
      s_g[tid]    = tok_g[(size_t)e * CAPC + gr];
      s_slot[tid] = tok_slot[(size_t)e * CAPC + gr];
    }
  }

  const int ar0 = tid >> 2;
  const int ac  = 8 * (((tid & 3) - (tid >> 3)) & 3);
  size_t arow0, arow1;
  if (AGATHER) {
    int g0 = m0 + ar0, g1 = m0 + 64 + ar0;
    int t0i = (g0 < cnt) ? tok_idx[(size_t)e * CAPC + g0] : 0;
    int t1i = (g1 < cnt) ? tok_idx[(size_t)e * CAPC + g1] : 0;
    arow0 = (size_t)t0i * KD; arow1 = (size_t)t1i * KD;
  } else {
    arow0 = ((size_t)e * CAPC + m0 + ar0) * KD;
    arow1 = arow0 + (size_t)64 * KD;
  }
  const unsigned short* ap0 = Abf + arow0 + ac;
  const unsigned short* ap1 = Abf + arow1 + ac;
  const int awb = (tid & 192) * 8;

  const int l = tid & 63, w = tid >> 6;
  const float* bp = Bw + (size_t)e * KD * ND + (size_t)(8 * w) * ND + n0 + 2 * l;

  float2 breg[4][8];

  auto stageA = [&](int t, int s) {
    glds16(&AL[s][0][0] + awb,        ap0 + t * 32);
    glds16(&AL[s][0][0] + 2048 + awb, ap1 + t * 32);
  };
  auto loadB = [&](int t, int p) {
    const float* pb = bp + (size_t)t * 32 * ND;
    #pragma unroll
    for (int j = 0; j < 8; j++) breg[p][j] = *(const float2*)(pb + (size_t)j * ND);
  };
  auto writeB = [&](int s, int p) {
    uint4 rx, ry;
    rx.x = cvt2(breg[p][0].x, breg[p][1].x); rx.y = cvt2(breg[p][2].x, breg[p][3].x);
    rx.z = cvt2(breg[p][4].x, breg[p][5].x); rx.w = cvt2(breg[p][6].x, breg[p][7].x);
    ry.x = cvt2(breg[p][0].y, breg[p][1].y); ry.y = cvt2(breg[p][2].y, breg[p][3].y);
    ry.z = cvt2(breg[p][4].y, breg[p][5].y); ry.w = cvt2(breg[p][6].y, breg[p][7].y);
    *(uint4*)&BL[s][2 * l][8 * w]     = rx;
    *(uint4*)&BL[s][2 * l + 1][8 * w] = ry;
  };

  const int lane = tid & 63, wv = tid >> 6;
  const int wm = (wv >> 1) * 64, wn = (wv & 1) * 64;
  const int li = lane & 15, lg = lane >> 4;
  const int kxa = 8 * ((lg + ((li >> 1) & 3)) & 3);

  f32x4 acc[4][4];
  #pragma unroll
  for (int i = 0; i < 4; i++)
    #pragma unroll
    for (int j = 0; j < 4; j++) acc[i][j] = (f32x4){0.f, 0.f, 0.f, 0.f};

  auto step = [&](int s) {
    bf16x8 afr[4], bfr[4];
    #pragma unroll
    for (int mi = 0; mi < 4; mi++)
      afr[mi] = *(const bf16x8*)&AL[s][wm + mi * 16 + li][kxa];
    #pragma unroll
    for (int ni = 0; ni < 4; ni++)
      bfr[ni] = *(const bf16x8*)&BL[s][wn + ni * 16 + li][lg * 8];
    __builtin_amdgcn_s_setprio(1);
    #pragma unroll
    for (int mi = 0; mi < 4; mi++)
      #pragma unroll
      for (int ni = 0; ni < 4; ni++)
        acc[mi][ni] = __builtin_amdgcn_mfma_f32_16x16x32_bf16(afr[mi], bfr[ni], acc[mi][ni], 0, 0, 0);
    __builtin_amdgcn_s_setprio(0);
  };

  loadB(0, 0);
  stageA(0, 0); loadB(1, 1);
  stageA(1, 1); loadB(2, 2);
  stageA(2, 2); loadB(3, 3);
  asm volatile("s_waitcnt vmcnt(28)" ::: "memory");
  writeB(0, 0);
  asm volatile("s_waitcnt lgkmcnt(0)" ::: "memory");
  __builtin_amdgcn_s_barrier();

  #define SUBITER(p)                                                        \
    do {                                                                    \
      const int jj = jb + (p);                                              \
      stageA(min(jj + 3, NK - 1), ((p) + 3) & 3);                           \
      loadB(min(jj + 4, NK - 1), (p));                                      \
      step(p);                                                              \
      asm volatile("s_waitcnt vmcnt(28)" ::: "memory");                     \
      writeB(((p) + 1) & 3, ((p) + 1) & 3);                                 \
      asm volatile("s_waitcnt lgkmcnt(0)" ::: "memory");                    \
      __builtin_amdgcn_s_barrier();                                         \
    } while (0)

  for (int jb = 0; jb < NK; jb += 4) {
    SUBITER(0); SUBITER(1); SUBITER(2); SUBITER(3);
  }
  #undef SUBITER
  asm volatile("s_waitcnt vmcnt(0)" ::: "memory");

  const float* bpb = bias + (size_t)e * ND;
  #pragma unroll
  for (int mi = 0; mi < 4; mi++) {
    #pragma unroll
    for (int ni = 0; ni < 4; ni++) {
      const int ncol = n0 + wn + ni * 16 + li;
      const float bb = bpb[ncol];
      #pragma unroll
      for (int qq = 0; qq < 4; qq++) {
        const int r = wm + mi * 16 + lg * 4 + qq;
        const int gr = m0 + r;
        if (gr < cnt) {
          float v = acc[mi][ni][qq] + bb;
          if (EPI == 0) {
            v = gelu_exact(v);
            ((unsigned short*)Outp)[((size_t)e * CAPC + gr) * ND + ncol] = f2bf(v);
          } else if (EPI == 1) {
            ((unsigned short*)Outp)[((size_t)e * CAPC + gr) * ND + ncol] = f2bf(v);
          } else {
            ((float*)Outp)[((size_t)s_tok[r] * KTOP + s_slot[r]) * OD + ncol] = v * s_g[r];
          }
        }
      }
    }
  }
}

// ---------------- combine 8 slots + LayerNorm -------------------------------------
__global__ __launch_bounds__(256) void combine_ln(
    const float* __restrict__ yd, const float* __restrict__ lw,
    const float* __restrict__ lb, float* __restrict__ out)
{
  const int t = blockIdx.x, tid = threadIdx.x;
  float v[3];
  #pragma unroll
  for (int i = 0; i < 3; i++) {
    const int c = tid + 256 * i;
    float s = 0.f;
    #pragma unroll
    for (int j = 0; j < KTOP; j++) s += yd[((size_t)t * KTOP + j) * OD + c];
    v[i] = s;
  }
  float s1 = v[0] + v[1] + v[2];
  float s2 = v[0] * v[0] + v[1] * v[1] + v[2] * v[2];
  #pragma unroll
  for (int off = 32; off > 0; off >>= 1) {
    s1 += __shfl_xor(s1, off);
    s2 += __shfl_xor(s2, off);
  }
  __shared__ float as1[4], as2[4];
  const int lane = tid & 63, wv = tid >> 6;
  if (lane == 0) { as1[wv] = s1; as2[wv] = s2; }
  __syncthreads();
  s1 = as1[0] + as1[1] + as1[2] + as1[3];
  s2 = as2[0] + as2[1] + as2[2] + as2[3];
  const float mu = s1 * (1.f / OD);
  const float var = s2 * (1.f / OD) - mu * mu;
  const float rstd = rsqrtf(var + 1e-5f);
  #pragma unroll
  for (int i = 0; i < 3; i++) {
    const int c = tid + 256 * i;
    out[(size_t)t * OD + c] = (v[i] - mu) * rstd * lw[c] + lb[c];
  }
}

extern "C" void kernel_launch(void* const* d_in, const int* in_sizes, int n_in,
                              void* d_out, int out_size, void* d_ws, size_t ws_size,
                              hipStream_t stream) {
  const float* x     = (const float*)d_in[0];
  const float* noise = (const float*)d_in[1];
  const float* Wr    = (const float*)d_in[2];
  const float* br    = (const float*)d_in[3];
  const float* Wn    = (const float*)d_in[4];
  const float* bn    = (const float*)d_in[5];
  const float* W1    = (const float*)d_in[6];
  const float* b1    = (const float*)d_in[7];
  const float* W2    = (const float*)d_in[8];
  const float* b2    = (const float*)d_in[9];
  const float* W3    = (const float*)d_in[10];
  const float* b3    = (const float*)d_in[11];
  const float* Wo    = (const float*)d_in[12];
  const float* bo    = (const float*)d_in[13];
  const float* lw    = (const float*)d_in[14];
  const float* lb    = (const float*)d_in[15];
  float* out = (float*)d_out;

  char* ws = (char*)d_ws;
  constexpr size_t OFF_GATE = 0;
  constexpr size_t OFF_SLOT = OFF_GATE + (size_t)T_TOK * NE * 4;
  constexpr size_t OFF_TIDX = OFF_SLOT + (size_t)T_TOK * NE * 4;
  constexpr size_t OFF_TG   = OFF_TIDX + (size_t)NE * CAPC * 4;
  constexpr size_t OFF_TSL  = OFF_TG + (size_t)NE * CAPC * 4;
  constexpr size_t OFF_CNT  = OFF_TSL + (size_t)NE * CAPC * 4;
  constexpr size_t OFF_YD   = ((OFF_CNT + NE * 4) + 255) & ~(size_t)255;
  constexpr size_t SZ_YD    = (size_t)T_TOK * KTOP * OD * 4;
  constexpr size_t OFF_H1   = OFF_YD + SZ_YD;
  constexpr size_t OFF_H2   = OFF_H1 + (size_t)NE * CAPC * HD * 2;
  constexpr size_t OFF_H3   = OFF_H2 + (size_t)NE * CAPC * HD * 2;
  constexpr size_t OFF_XBF  = OFF_H3 + (size_t)NE * CAPC * BTD * 2;

  float* gate = (float*)(ws + OFF_GATE);
  int*   slot = (int*)(ws + OFF_SLOT);
  int*   tidx = (int*)(ws + OFF_TIDX);
  float* tg   = (float*)(ws + OFF_TG);
  int*   tsl  = (int*)(ws + OFF_TSL);
  int*   cnts = (int*)(ws + OFF_CNT);
  float* yd   = (float*)(ws + OFF_YD);
  unsigned short* h1  = (unsigned short*)(ws + OFF_H1);
  unsigned short* h2  = (unsigned short*)(ws + OFF_H2);
  unsigned short* h3  = (unsigned short*)(ws + OFF_H3);
  unsigned short* xbf = (unsigned short*)(ws + OFF_XBF);

  hipMemsetAsync(yd, 0, SZ_YD, stream);
  cvt_x<<<T_TOK * DIN / 4 / 256, 256, 0, stream>>>(x, xbf);
  router_kernel<<<T_TOK / 8, 256, 0, stream>>>(x, noise, Wr, br, Wn, bn, gate, slot);
  dispatch_kernel<<<NE, 256, 0, stream>>>(gate, slot, tidx, tg, tsl, cnts);
  // G1: 16 n-panels x 2 m x 64 e -> BPE=32, XCD-grouped, 2 blocks/CU
  moe_gemm_big<DIN, HD, true, 0, 16, 32><<<2048, 512, 0, stream>>>(
      xbf, W1, b1, h1, tidx, tg, tsl, cnts);
  // G2: same geometry
  moe_gemm_big<HD, HD, false, 0, 16, 32><<<2048, 512, 0, stream>>>(
      h1, W2, b2, h2, tidx, tg, tsl, cnts);
  // G3: 2 n x 4 m x 64 e -> BPE=8
  moe_gemm<HD, BTD, false, 1, 2, 8><<<512, 256, 0, stream>>>(
      h2, W3, b3, h3, tidx, tg, tsl, cnts);
  // G4: 6 n x 4 m x 64 e -> BPE=24
  moe_gemm<BTD, OD, false, 2, 6, 24><<<1536, 256, 0, stream>>>(
      h3, Wo, bo, yd, tidx, tg, tsl, cnts);
  combine_ln<<<T_TOK, 256, 0, stream>>>(yd, lw, lb, out);
}